// Round 1
// baseline (178.498 us; speedup 1.0000x reference)
//
#include <hip/hip_runtime.h>

static constexpr int NN = 100000;   // nodes
static constexpr int NE = 500000;   // edges
static constexpr int D  = 32;       // channels
static constexpr int NR = 16;       // relations

// ---------------- K1: h = x @ W ----------------
__global__ __launch_bounds__(256) void k_xw(const float* __restrict__ x,
                                            const float* __restrict__ W,
                                            float* __restrict__ h) {
    __shared__ float sW[D * D];
    for (int i = threadIdx.x; i < D * D; i += 256) sW[i] = W[i];
    __syncthreads();
    int n = blockIdx.x * 256 + threadIdx.x;
    if (n >= NN) return;
    float xr[D];
    const float4* xv = reinterpret_cast<const float4*>(x + (size_t)n * D);
    #pragma unroll
    for (int k = 0; k < 8; ++k) {
        float4 v = xv[k];
        xr[4*k+0] = v.x; xr[4*k+1] = v.y; xr[4*k+2] = v.z; xr[4*k+3] = v.w;
    }
    float4* hv = reinterpret_cast<float4*>(h + (size_t)n * D);
    #pragma unroll
    for (int oc = 0; oc < 8; ++oc) {
        float a0 = 0.f, a1 = 0.f, a2 = 0.f, a3 = 0.f;
        #pragma unroll
        for (int i = 0; i < D; ++i) {
            float xi = xr[i];
            a0 += xi * sW[i*D + 4*oc + 0];
            a1 += xi * sW[i*D + 4*oc + 1];
            a2 += xi * sW[i*D + 4*oc + 2];
            a3 += xi * sW[i*D + 4*oc + 3];
        }
        hv[oc] = make_float4(a0, a1, a2, a3);
    }
}

// ---------------- K2: per-edge matvec + scatter-add ----------------
// 16 relation matrices (64 KB) staged in LDS; one half-wave per edge;
// lane o computes output channel o. atomicAdd into acc (= d_out).
__global__ __launch_bounds__(256) void k_edge(const float* __restrict__ h,
                                              const int* __restrict__ ei,
                                              const int* __restrict__ et,
                                              const float* __restrict__ rel,
                                              float* __restrict__ acc) {
    __shared__ float sR[NR * D * D];   // 64 KB
    {
        const float4* rv = reinterpret_cast<const float4*>(rel);
        float4* sv = reinterpret_cast<float4*>(sR);
        for (int i = threadIdx.x; i < NR * D * D / 4; i += 256) sv[i] = rv[i];
    }
    __syncthreads();
    const int o   = threadIdx.x & 31;
    const int sub = threadIdx.x >> 5;                 // 0..7 half-waves/block
    for (int e = blockIdx.x * 8 + sub; e < NE; e += gridDim.x * 8) {
        int src = ei[e];
        int dst = ei[NE + e];
        int t   = et[e];
        float hr[D];
        const float4* hv = reinterpret_cast<const float4*>(h + (size_t)src * D);
        #pragma unroll
        for (int k = 0; k < 8; ++k) {
            float4 v = hv[k];
            hr[4*k+0] = v.x; hr[4*k+1] = v.y; hr[4*k+2] = v.z; hr[4*k+3] = v.w;
        }
        const float* R = sR + t * (D * D);
        float m = 0.f;
        #pragma unroll
        for (int i = 0; i < D; ++i) m += hr[i] * R[i * D + o];
        atomicAdd(acc + (size_t)dst * D + o, m);
    }
}

// ---------------- K3a: scores + per-block max ----------------
__global__ __launch_bounds__(256) void k_score(const float* __restrict__ acc,
                                               const float* __restrict__ att,
                                               float* __restrict__ scores,
                                               float* __restrict__ pmax) {
    __shared__ float sA[D];
    if (threadIdx.x < D) sA[threadIdx.x] = att[threadIdx.x];
    __syncthreads();
    float lmax = -3.4e38f;
    for (int n = blockIdx.x * 256 + threadIdx.x; n < NN; n += gridDim.x * 256) {
        const float4* av = reinterpret_cast<const float4*>(acc + (size_t)n * D);
        float s = 0.f;
        #pragma unroll
        for (int k = 0; k < 8; ++k) {
            float4 v = av[k];
            s += v.x * sA[4*k+0] + v.y * sA[4*k+1] + v.z * sA[4*k+2] + v.w * sA[4*k+3];
        }
        scores[n] = s;
        lmax = fmaxf(lmax, s);
    }
    #pragma unroll
    for (int off = 32; off > 0; off >>= 1)
        lmax = fmaxf(lmax, __shfl_down(lmax, off, 64));
    __shared__ float wmax[4];
    if ((threadIdx.x & 63) == 0) wmax[threadIdx.x >> 6] = lmax;
    __syncthreads();
    if (threadIdx.x == 0)
        pmax[blockIdx.x] = fmaxf(fmaxf(wmax[0], wmax[1]), fmaxf(wmax[2], wmax[3]));
}

// ---------------- K3b: global max + sum(exp) (single block) ----------------
__global__ __launch_bounds__(1024) void k_reduce(const float* __restrict__ scores,
                                                 const float* __restrict__ pmax,
                                                 int nb,
                                                 float* __restrict__ MS) {
    __shared__ float sh[16];
    __shared__ float sM;
    int t = threadIdx.x;
    float lmax = -3.4e38f;
    for (int i = t; i < nb; i += 1024) lmax = fmaxf(lmax, pmax[i]);
    #pragma unroll
    for (int off = 32; off > 0; off >>= 1)
        lmax = fmaxf(lmax, __shfl_down(lmax, off, 64));
    if ((t & 63) == 0) sh[t >> 6] = lmax;
    __syncthreads();
    if (t == 0) {
        float m = sh[0];
        for (int w = 1; w < 16; ++w) m = fmaxf(m, sh[w]);
        sM = m;
    }
    __syncthreads();
    float M = sM;
    float lsum = 0.f;
    for (int n = t; n < NN; n += 1024) lsum += expf(scores[n] - M);
    #pragma unroll
    for (int off = 32; off > 0; off >>= 1)
        lsum += __shfl_down(lsum, off, 64);
    __syncthreads();
    if ((t & 63) == 0) sh[t >> 6] = lsum;
    __syncthreads();
    if (t == 0) {
        float s = 0.f;
        for (int w = 0; w < 16; ++w) s += sh[w];
        MS[0] = M;
        MS[1] = s;
    }
}

// ---------------- K3c: out = relu(acc * softmax_weight) ----------------
__global__ __launch_bounds__(256) void k_final(float* __restrict__ out,
                                               const float* __restrict__ scores,
                                               const float* __restrict__ MS) {
    int idx = blockIdx.x * 256 + threadIdx.x;      // float4 index
    if (idx >= NN * (D / 4)) return;
    int n = idx >> 3;                              // 8 float4 per row
    float w = expf(scores[n] - MS[0]) / MS[1];
    float4* p = reinterpret_cast<float4*>(out);
    float4 v = p[idx];
    v.x = fmaxf(v.x * w, 0.f);
    v.y = fmaxf(v.y * w, 0.f);
    v.z = fmaxf(v.z * w, 0.f);
    v.w = fmaxf(v.w * w, 0.f);
    p[idx] = v;
}

extern "C" void kernel_launch(void* const* d_in, const int* in_sizes, int n_in,
                              void* d_out, int out_size, void* d_ws, size_t ws_size,
                              hipStream_t stream) {
    const float* x   = (const float*)d_in[0];
    const int*   ei  = (const int*)  d_in[1];
    const int*   et  = (const int*)  d_in[2];
    const float* W   = (const float*)d_in[3];
    const float* rel = (const float*)d_in[4];
    const float* att = (const float*)d_in[5];
    float* out = (float*)d_out;

    // workspace layout (floats): h[NN*D] | scores[NN] | pmax[512] | MS[2]
    float* h      = (float*)d_ws;
    float* scores = h + (size_t)NN * D;
    float* pmax   = scores + NN;
    float* MS     = pmax + 512;

    // acc accumulates in d_out; zero it each call (deterministic).
    hipMemsetAsync(d_out, 0, (size_t)NN * D * sizeof(float), stream);

    int nb_xw = (NN + 255) / 256;
    k_xw<<<nb_xw, 256, 0, stream>>>(x, W, h);

    k_edge<<<512, 256, 0, stream>>>(h, ei, et, rel, out);

    k_score<<<512, 256, 0, stream>>>(out, att, scores, pmax);
    k_reduce<<<1, 1024, 0, stream>>>(scores, pmax, 512, MS);

    int nb_fin = (NN * (D / 4) + 255) / 256;
    k_final<<<nb_fin, 256, 0, stream>>>(out, scores, MS);
}

// Round 2
// 125.264 us; speedup vs baseline: 1.4250x; 1.4250x over previous
//
#include <hip/hip_runtime.h>

static constexpr int NN = 100000;   // nodes
static constexpr int NE = 500000;   // edges
static constexpr int D  = 32;       // channels
static constexpr int NR = 16;       // relations

// ---------------- K1: h = x @ W ----------------
__global__ __launch_bounds__(256) void k_xw(const float* __restrict__ x,
                                            const float* __restrict__ W,
                                            float* __restrict__ h) {
    __shared__ float sW[D * D];
    for (int i = threadIdx.x; i < D * D; i += 256) sW[i] = W[i];
    __syncthreads();
    int n = blockIdx.x * 256 + threadIdx.x;
    if (n >= NN) return;
    float xr[D];
    const float4* xv = reinterpret_cast<const float4*>(x + (size_t)n * D);
    #pragma unroll
    for (int k = 0; k < 8; ++k) {
        float4 v = xv[k];
        xr[4*k+0] = v.x; xr[4*k+1] = v.y; xr[4*k+2] = v.z; xr[4*k+3] = v.w;
    }
    float4* hv = reinterpret_cast<float4*>(h + (size_t)n * D);
    #pragma unroll
    for (int oc = 0; oc < 8; ++oc) {
        float a0 = 0.f, a1 = 0.f, a2 = 0.f, a3 = 0.f;
        #pragma unroll
        for (int i = 0; i < D; ++i) {
            float xi = xr[i];
            a0 += xi * sW[i*D + 4*oc + 0];
            a1 += xi * sW[i*D + 4*oc + 1];
            a2 += xi * sW[i*D + 4*oc + 2];
            a3 += xi * sW[i*D + 4*oc + 3];
        }
        hv[oc] = make_float4(a0, a1, a2, a3);
    }
}

// ---------------- K2: per-edge matvec + scatter-add ----------------
// 16 relation matrices (64 KB) in LDS; 512-thread blocks -> 2 blocks/CU
// (128 KB LDS) = 16 waves/CU. Each half-wave processes an edge PAIR per
// iteration (both gathers in flight) for 2x memory-level parallelism.
__global__ __launch_bounds__(512, 4) void k_edge(const float* __restrict__ h,
                                                 const int* __restrict__ ei,
                                                 const int* __restrict__ et,
                                                 const float* __restrict__ rel,
                                                 float* __restrict__ acc) {
    __shared__ float sR[NR * D * D];   // 64 KB
    {
        const float4* rv = reinterpret_cast<const float4*>(rel);
        float4* sv = reinterpret_cast<float4*>(sR);
        for (int i = threadIdx.x; i < NR * D * D / 4; i += 512) sv[i] = rv[i];
    }
    __syncthreads();
    const int o   = threadIdx.x & 31;
    const int sub = threadIdx.x >> 5;                 // 0..15 half-waves/block
    const int ghw = blockIdx.x * 16 + sub;
    const int nhw = gridDim.x * 16;
    for (int p = ghw; p < NE / 2; p += nhw) {
        const int e0 = 2 * p, e1 = 2 * p + 1;
        const int s0 = ei[e0],      s1 = ei[e1];
        const int d0 = ei[NE + e0], d1 = ei[NE + e1];
        const int t0 = et[e0],      t1 = et[e1];
        float4 a[8], b[8];
        const float4* h0 = reinterpret_cast<const float4*>(h + (size_t)s0 * D);
        const float4* h1 = reinterpret_cast<const float4*>(h + (size_t)s1 * D);
        #pragma unroll
        for (int k = 0; k < 8; ++k) a[k] = h0[k];
        #pragma unroll
        for (int k = 0; k < 8; ++k) b[k] = h1[k];
        const float* R0 = sR + t0 * (D * D);
        const float* R1 = sR + t1 * (D * D);
        float m0 = 0.f, m1 = 0.f;
        #pragma unroll
        for (int k = 0; k < 8; ++k) {
            m0 += a[k].x * R0[(4*k+0)*D + o];
            m0 += a[k].y * R0[(4*k+1)*D + o];
            m0 += a[k].z * R0[(4*k+2)*D + o];
            m0 += a[k].w * R0[(4*k+3)*D + o];
            m1 += b[k].x * R1[(4*k+0)*D + o];
            m1 += b[k].y * R1[(4*k+1)*D + o];
            m1 += b[k].z * R1[(4*k+2)*D + o];
            m1 += b[k].w * R1[(4*k+3)*D + o];
        }
        atomicAdd(acc + (size_t)d0 * D + o, m0);
        atomicAdd(acc + (size_t)d1 * D + o, m1);
    }
}

// ---------------- K3a: scores + per-block online (max, sum-exp) ----------
__global__ __launch_bounds__(256) void k_score(const float* __restrict__ acc,
                                               const float* __restrict__ att,
                                               float* __restrict__ scores,
                                               float* __restrict__ pmax,
                                               float* __restrict__ psum) {
    __shared__ float sA[D];
    __shared__ float shm[4], shs[4];
    if (threadIdx.x < D) sA[threadIdx.x] = att[threadIdx.x];
    __syncthreads();
    const int n = blockIdx.x * 256 + threadIdx.x;
    float s = -3.4e38f;
    if (n < NN) {
        const float4* av = reinterpret_cast<const float4*>(acc + (size_t)n * D);
        float v0 = 0.f;
        #pragma unroll
        for (int k = 0; k < 8; ++k) {
            float4 v = av[k];
            v0 += v.x * sA[4*k+0] + v.y * sA[4*k+1] + v.z * sA[4*k+2] + v.w * sA[4*k+3];
        }
        scores[n] = v0;
        s = v0;
    }
    // block max
    float m = s;
    #pragma unroll
    for (int off = 32; off > 0; off >>= 1)
        m = fmaxf(m, __shfl_down(m, off, 64));
    if ((threadIdx.x & 63) == 0) shm[threadIdx.x >> 6] = m;
    __syncthreads();
    const float bm = fmaxf(fmaxf(shm[0], shm[1]), fmaxf(shm[2], shm[3]));
    // block sum of exp(s - bm)
    float e = (n < NN) ? expf(s - bm) : 0.f;
    #pragma unroll
    for (int off = 32; off > 0; off >>= 1)
        e += __shfl_down(e, off, 64);
    if ((threadIdx.x & 63) == 0) shs[threadIdx.x >> 6] = e;
    __syncthreads();
    if (threadIdx.x == 0) {
        pmax[blockIdx.x] = bm;
        psum[blockIdx.x] = shs[0] + shs[1] + shs[2] + shs[3];
    }
}

// ---------------- K3b: combine per-block (m,s) pairs (1 block) -----------
__global__ __launch_bounds__(256) void k_combine(const float* __restrict__ pmax,
                                                 const float* __restrict__ psum,
                                                 int nb,
                                                 float* __restrict__ MS) {
    __shared__ float shm[4], shs[4];
    const int t = threadIdx.x;
    float m = -3.4e38f, s = 0.f;
    for (int i = t; i < nb; i += 256) {
        float mi = pmax[i], si = psum[i];
        float M = fmaxf(m, mi);
        s = s * expf(m - M) + si * expf(mi - M);
        m = M;
    }
    #pragma unroll
    for (int off = 32; off > 0; off >>= 1) {
        float mo = __shfl_down(m, off, 64);
        float so = __shfl_down(s, off, 64);
        float M = fmaxf(m, mo);
        s = s * expf(m - M) + so * expf(mo - M);
        m = M;
    }
    if ((t & 63) == 0) { shm[t >> 6] = m; shs[t >> 6] = s; }
    __syncthreads();
    if (t == 0) {
        float M = shm[0], S = shs[0];
        for (int w = 1; w < 4; ++w) {
            float Mn = fmaxf(M, shm[w]);
            S = S * expf(M - Mn) + shs[w] * expf(shm[w] - Mn);
            M = Mn;
        }
        MS[0] = M;
        MS[1] = S;
    }
}

// ---------------- K3c: out = relu(acc * softmax_weight) ----------------
__global__ __launch_bounds__(256) void k_final(float* __restrict__ out,
                                               const float* __restrict__ scores,
                                               const float* __restrict__ MS) {
    int idx = blockIdx.x * 256 + threadIdx.x;      // float4 index
    if (idx >= NN * (D / 4)) return;
    int n = idx >> 3;                              // 8 float4 per row
    float w = expf(scores[n] - MS[0]) / MS[1];
    float4* p = reinterpret_cast<float4*>(out);
    float4 v = p[idx];
    v.x = fmaxf(v.x * w, 0.f);
    v.y = fmaxf(v.y * w, 0.f);
    v.z = fmaxf(v.z * w, 0.f);
    v.w = fmaxf(v.w * w, 0.f);
    p[idx] = v;
}

extern "C" void kernel_launch(void* const* d_in, const int* in_sizes, int n_in,
                              void* d_out, int out_size, void* d_ws, size_t ws_size,
                              hipStream_t stream) {
    const float* x   = (const float*)d_in[0];
    const int*   ei  = (const int*)  d_in[1];
    const int*   et  = (const int*)  d_in[2];
    const float* W   = (const float*)d_in[3];
    const float* rel = (const float*)d_in[4];
    const float* att = (const float*)d_in[5];
    float* out = (float*)d_out;

    // workspace (floats): h[NN*D] | scores[NN] | pmax[512] | psum[512] | MS[2]
    float* h      = (float*)d_ws;
    float* scores = h + (size_t)NN * D;
    float* pmax   = scores + NN;
    float* psum   = pmax + 512;
    float* MS     = psum + 512;

    hipMemsetAsync(d_out, 0, (size_t)NN * D * sizeof(float), stream);

    const int nb_n = (NN + 255) / 256;           // 391
    k_xw<<<nb_n, 256, 0, stream>>>(x, W, h);

    k_edge<<<512, 512, 0, stream>>>(h, ei, et, rel, out);

    k_score<<<nb_n, 256, 0, stream>>>(out, att, scores, pmax, psum);
    k_combine<<<1, 256, 0, stream>>>(pmax, psum, nb_n, MS);

    const int nb_fin = (NN * (D / 4) + 255) / 256;
    k_final<<<nb_fin, 256, 0, stream>>>(out, scores, MS);
}